// Round 1
// baseline (196.912 us; speedup 1.0000x reference)
//
#include <hip/hip_runtime.h>

// SecureOptimizedBlockReLU on (16,128,114,114) fp32.
// ch 0-31: passthrough. ch 32-79: 2x2 block sign mask. ch 80-127: 4x4 (padded).
// sign = (int64)trunc(f32 block sum) >= 0  <=>  f32_sum > -1.0f
// (floor-div/shift chain by positive constants preserves sign; int16 wrap unreachable).

#define NN 16
#define CC 128
#define HH 114
#define WW 114
#define PLANE (HH * WW)  // 12996 floats, 51984 B (16B-aligned plane starts, 8B-aligned rows)

// ---- ch 0..31: pure float4 copy (plane = 3249 float4, aligned) ----
__global__ __launch_bounds__(256) void copy_kernel(const float4* __restrict__ in,
                                                   float4* __restrict__ out) {
    const int per_n    = 32 * PLANE / 4;   // 103968 float4 per n (ch 0..31 contiguous)
    const int stride_n = CC * PLANE / 4;   // 415872 float4 per n
    int idx = blockIdx.x * blockDim.x + threadIdx.x;
    if (idx >= NN * per_n) return;
    int n = idx / per_n;
    int r = idx - n * per_n;
    int off = n * stride_n + r;
    out[off] = in[off];
}

// ---- ch 32..79: one thread per 2x2 block. 57x57 blocks/plane, 768 planes ----
__global__ __launch_bounds__(256) void relu2_kernel(const float* __restrict__ in,
                                                    float* __restrict__ out) {
    int tid = blockIdx.x * blockDim.x + threadIdx.x;
    if (tid >= 768 * 3249) return;
    int plane = tid / 3249;
    int b     = tid - plane * 3249;
    int bh    = b / 57;
    int bw    = b - bh * 57;
    int n  = plane / 48;
    int c  = plane - n * 48;                 // 0..47 -> channel 32+c
    int base = (n * CC + 32 + c) * PLANE;    // < 2^31, int ok
    int h0 = 2 * bh, w0 = 2 * bw;
    const float* p0 = in + base + h0 * WW + w0;
    const float* p1 = p0 + WW;
    float2 a = *(const float2*)p0;           // 8B aligned: rows 456B, w0 even
    float2 d = *(const float2*)p1;
    // row-major sequential f32 sum: x00 + x01 + x10 + x11
    float s = a.x + a.y + d.x + d.y;
    float m = (s > -1.0f) ? 1.0f : 0.0f;
    *(float2*)(out + base + h0 * WW + w0)       = make_float2(a.x * m, a.y * m);
    *(float2*)(out + base + (h0 + 1) * WW + w0) = make_float2(d.x * m, d.y * m);
}

// ---- ch 80..127: one thread per 4x4 block. 29x29 blocks/plane (edges are 2-wide), 768 planes ----
__global__ __launch_bounds__(256) void relu4_kernel(const float* __restrict__ in,
                                                    float* __restrict__ out) {
    int tid = blockIdx.x * blockDim.x + threadIdx.x;
    if (tid >= 768 * 841) return;
    int plane = tid / 841;
    int b     = tid - plane * 841;
    int bh    = b / 29;
    int bw    = b - bh * 29;
    int n  = plane / 48;
    int c  = plane - n * 48;                 // 0..47 -> channel 80+c
    int base = (n * CC + 80 + c) * PLANE;
    int h0 = 4 * bh, w0 = 4 * bw;
    int nh = (h0 + 4 <= HH) ? 4 : (HH - h0); // 4 or 2
    int nw = (w0 + 4 <= WW) ? 4 : (WW - w0); // 4 or 2
    float x[4][4];
#pragma unroll
    for (int r = 0; r < 4; ++r) {
        if (r < nh) {
            const float* rp = in + base + (h0 + r) * WW + w0;
            float2 lo = *(const float2*)rp;  // 8B aligned (w0 mult of 4)
            x[r][0] = lo.x; x[r][1] = lo.y;
            if (nw == 4) {
                float2 hi = *(const float2*)(rp + 2);
                x[r][2] = hi.x; x[r][3] = hi.y;
            } else {
                x[r][2] = 0.0f; x[r][3] = 0.0f;
            }
        } else {
            x[r][0] = x[r][1] = x[r][2] = x[r][3] = 0.0f;
        }
    }
    // row-major sequential f32 sum (pad zeros are exact no-ops)
    float s = 0.0f;
#pragma unroll
    for (int r = 0; r < 4; ++r)
#pragma unroll
        for (int j = 0; j < 4; ++j) s += x[r][j];
    float m = (s > -1.0f) ? 1.0f : 0.0f;
    for (int r = 0; r < nh; ++r) {
        float* op = out + base + (h0 + r) * WW + w0;
        *(float2*)op = make_float2(x[r][0] * m, x[r][1] * m);
        if (nw == 4) *(float2*)(op + 2) = make_float2(x[r][2] * m, x[r][3] * m);
    }
}

extern "C" void kernel_launch(void* const* d_in, const int* in_sizes, int n_in,
                              void* d_out, int out_size, void* d_ws, size_t ws_size,
                              hipStream_t stream) {
    const float* in = (const float*)d_in[0];
    float* out = (float*)d_out;

    // ch 0..31 copy: 16 * 103968 float4 = 1,663,488 -> 6498 blocks of 256 (exact)
    copy_kernel<<<6498, 256, 0, stream>>>((const float4*)in, (float4*)out);
    // 2x2: 768 * 3249 = 2,495,232 threads -> 9747 blocks (exact)
    relu2_kernel<<<9747, 256, 0, stream>>>(in, out);
    // 4x4: 768 * 841 = 645,888 threads -> 2523 blocks (exact)
    relu4_kernel<<<2523, 256, 0, stream>>>(in, out);
}

// Round 2
// 192.196 us; speedup vs baseline: 1.0245x; 1.0245x over previous
//
#include <hip/hip_runtime.h>

// SecureOptimizedBlockReLU on (16,128,114,114) fp32 — single fused kernel.
// ch 0-31: passthrough. ch 32-79: 2x2 block sign mask. ch 80-127: 4x4 (padded).
// sign = (int64)trunc(f32 block sum) >= 0  <=>  f32_sum > -1.0f
// (floor-div/shift chain by positive constants preserves sign; int16 wrap unreachable;
//  verified absmax 0.0 in R1).
//
// Grid-sliced fusion: blocks [0,6498) copy ch0-31 (float4),
//                     blocks [6498,11457) handle 2x2 (unit = 4w x 2h region),
//                     blocks [11457,13980) handle 4x4 (unit = one block).
// Alignment: plane = 12996 floats (mult of 4) -> even rows 16B-aligned (float4),
// odd rows offset ≡ 2 mod 4 -> float2 pairs (8B-aligned).

#define CC 128
#define WW 114
#define PLANE 12996

#define NBLK_A 6498   // 16*32*3249 float4 units / 256
#define NBLK_B 4959   // 768 planes * 57 block-rows * 29 units / 256
#define NBLK_C 2523   // 768 planes * 841 blocks / 256

__global__ __launch_bounds__(256) void fused_sbrelu_kernel(const float* __restrict__ in,
                                                           float* __restrict__ out) {
    const int bid = blockIdx.x;
    const int tid = threadIdx.x;

    if (bid < NBLK_A) {
        // ---- class A: ch 0..31 pure float4 copy ----
        int idx = bid * 256 + tid;              // < 1,663,488
        int n = idx / 103968;                   // 32 * 3249 float4 per n
        int r = idx - n * 103968;
        int off = n * 415872 + r;               // CC*PLANE/4 per n; max < 2^31
        ((float4*)out)[off] = ((const float4*)in)[off];
    } else if (bid < NBLK_A + NBLK_B) {
        // ---- class B: ch 32..79, 2x2 blocks; unit = 2 horizontally-adjacent blocks ----
        int u = (bid - NBLK_A) * 256 + tid;     // < 1,269,504
        int plane = u / 1653;                   // 57 * 29
        int rest  = u - plane * 1653;
        int r = rest / 29;                      // block-row 0..56
        int j = rest - r * 29;                  // unit col 0..28
        int n = plane / 48;
        int c = plane - n * 48 + 32;
        int base = (n * CC + c) * PLANE;
        int e0 = 228 * r + 4 * j;               // even row, ≡0 mod 4 (16B aligned)
        const float* bi = in + base;
        float*       bo = out + base;
        if (j < 28) {
            float4 a  = *(const float4*)(bi + e0);
            float2 b0 = *(const float2*)(bi + e0 + WW);
            float2 b1 = *(const float2*)(bi + e0 + WW + 2);
            // row-major sequential f32 sums (matches reference at trunc boundary)
            float s0 = a.x + a.y + b0.x + b0.y;
            float s1 = a.z + a.w + b1.x + b1.y;
            float m0 = (s0 > -1.0f) ? 1.0f : 0.0f;
            float m1 = (s1 > -1.0f) ? 1.0f : 0.0f;
            *(float4*)(bo + e0)          = make_float4(a.x*m0, a.y*m0, a.z*m1, a.w*m1);
            *(float2*)(bo + e0 + WW)     = make_float2(b0.x*m0, b0.y*m0);
            *(float2*)(bo + e0 + WW + 2) = make_float2(b1.x*m1, b1.y*m1);
        } else {
            // last 2 columns (w0 = 112)
            float2 a = *(const float2*)(bi + e0);
            float2 b = *(const float2*)(bi + e0 + WW);
            float s = a.x + a.y + b.x + b.y;
            float m = (s > -1.0f) ? 1.0f : 0.0f;
            *(float2*)(bo + e0)      = make_float2(a.x*m, a.y*m);
            *(float2*)(bo + e0 + WW) = make_float2(b.x*m, b.y*m);
        }
    } else {
        // ---- class C: ch 80..127, 4x4 blocks (edges 2-wide/2-tall) ----
        int u = (bid - NBLK_A - NBLK_B) * 256 + tid;  // < 645,888
        int plane = u / 841;                    // 29 * 29
        int rest  = u - plane * 841;
        int bh = rest / 29;
        int bw = rest - bh * 29;
        int n = plane / 48;
        int c = plane - n * 48 + 80;
        int base = (n * CC + c) * PLANE;
        int h0 = 4 * bh, w0 = 4 * bw;
        int nh = (bh == 28) ? 2 : 4;
        int nw = (bw == 28) ? 2 : 4;
        const float* bi = in + base;
        float*       bo = out + base;
        float x[4][4];
#pragma unroll
        for (int r = 0; r < 4; ++r) {
            if (r < nh) {
                int er = (h0 + r) * WW + w0;    // r even: ≡0 mod 4; r odd: ≡2 mod 4
                if (nw == 4) {
                    if ((r & 1) == 0) {
                        float4 v = *(const float4*)(bi + er);
                        x[r][0] = v.x; x[r][1] = v.y; x[r][2] = v.z; x[r][3] = v.w;
                    } else {
                        float2 lo = *(const float2*)(bi + er);
                        float2 hi = *(const float2*)(bi + er + 2);
                        x[r][0] = lo.x; x[r][1] = lo.y; x[r][2] = hi.x; x[r][3] = hi.y;
                    }
                } else {
                    float2 lo = *(const float2*)(bi + er);
                    x[r][0] = lo.x; x[r][1] = lo.y; x[r][2] = 0.0f; x[r][3] = 0.0f;
                }
            } else {
                x[r][0] = x[r][1] = x[r][2] = x[r][3] = 0.0f;
            }
        }
        // row-major sequential f32 sum (pad zeros exact no-ops)
        float s = 0.0f;
#pragma unroll
        for (int r = 0; r < 4; ++r)
#pragma unroll
            for (int j = 0; j < 4; ++j) s += x[r][j];
        float m = (s > -1.0f) ? 1.0f : 0.0f;
#pragma unroll
        for (int r = 0; r < 4; ++r) {
            if (r < nh) {
                int er = (h0 + r) * WW + w0;
                if (nw == 4) {
                    if ((r & 1) == 0) {
                        *(float4*)(bo + er) = make_float4(x[r][0]*m, x[r][1]*m, x[r][2]*m, x[r][3]*m);
                    } else {
                        *(float2*)(bo + er)     = make_float2(x[r][0]*m, x[r][1]*m);
                        *(float2*)(bo + er + 2) = make_float2(x[r][2]*m, x[r][3]*m);
                    }
                } else {
                    *(float2*)(bo + er) = make_float2(x[r][0]*m, x[r][1]*m);
                }
            }
        }
    }
}

extern "C" void kernel_launch(void* const* d_in, const int* in_sizes, int n_in,
                              void* d_out, int out_size, void* d_ws, size_t ws_size,
                              hipStream_t stream) {
    const float* in = (const float*)d_in[0];
    float* out = (float*)d_out;
    fused_sbrelu_kernel<<<NBLK_A + NBLK_B + NBLK_C, 256, 0, stream>>>(in, out);
}

// Round 3
// 190.361 us; speedup vs baseline: 1.0344x; 1.0096x over previous
//
#include <hip/hip_runtime.h>

// SecureOptimizedBlockReLU (16,128,114,114) fp32 — one workgroup per (n,c) plane.
// ch 0-31 passthrough; ch 32-79 2x2 block sign; ch 80-127 4x4 (zero-padded edges).
// sign = f32_block_sum > -1.0f  (trunc/floordiv/shift chain preserves sign class;
// int16 wrap unreachable; row-major sequential f32 sum order — absmax 0.0 in R1/R2).
//
// R2 showed 2.4 TB/s: strided float2 wave patterns inflate cache-line transactions.
// This version: ALL global traffic is contiguous 16B-aligned per-wave streams.
// Plane (51984 B) staged in LDS; masks computed from LDS; nontemporal writeout.

typedef float v4 __attribute__((ext_vector_type(4)));

#define PLANE 12996
#define P4 3249   // float4 per plane; 3249 = 12*256 + 177

__global__ __launch_bounds__(256) void sbrelu_plane_kernel(const float* __restrict__ in,
                                                           float* __restrict__ out) {
    __shared__ float Lp[PLANE];   // 51984 B plane
    __shared__ float Lm[P4];      // 12996 B masks (only [0,3249) for 2x2, [0,841) for 4x4)
    const int wg  = blockIdx.x;   // n*128 + c  (NCHW contiguous -> base = wg*PLANE)
    const int c   = wg & 127;
    const int tid = threadIdx.x;
    const v4* __restrict__ ip = (const v4*)(in + (size_t)wg * PLANE);
    v4* __restrict__       op = (v4*)(out + (size_t)wg * PLANE);

    if (c < 32) {
        // ---- passthrough: pure contiguous float4 copy, no barriers ----
        v4 r[12];
#pragma unroll
        for (int i = 0; i < 12; ++i) r[i] = ip[tid + 256 * i];
        v4 rt;
        if (tid < 177) rt = ip[tid + 3072];
#pragma unroll
        for (int i = 0; i < 12; ++i) __builtin_nontemporal_store(r[i], &op[tid + 256 * i]);
        if (tid < 177) __builtin_nontemporal_store(rt, &op[tid + 3072]);
        return;
    }

    // ---- phase 1: stage plane into LDS (contiguous coalesced float4 stream) ----
    {
        v4 r[12];
#pragma unroll
        for (int i = 0; i < 12; ++i) r[i] = ip[tid + 256 * i];
        v4 rt;
        if (tid < 177) rt = ip[tid + 3072];
#pragma unroll
        for (int i = 0; i < 12; ++i) *(v4*)&Lp[4 * (tid + 256 * i)] = r[i];
        if (tid < 177) *(v4*)&Lp[4 * (tid + 3072)] = rt;
    }
    __syncthreads();

    // ---- phase 2: per-block masks (bit-exact row-major sequential f32 sums) ----
    if (c < 80) {
        // 2x2: 57x57 = 3249 blocks
        for (int b = tid; b < 3249; b += 256) {
            int bh = b / 57, bw = b - bh * 57;
            const float* p = &Lp[228 * bh + 2 * bw];
            float s = ((p[0] + p[1]) + p[114]) + p[115];
            Lm[b] = (s > -1.0f) ? 1.0f : 0.0f;
        }
    } else {
        // 4x4: 29x29 = 841 blocks (edge blocks 2-wide/2-tall; pad zeros are exact no-ops)
        for (int b = tid; b < 841; b += 256) {
            int bh = b / 29, bw = b - bh * 29;
            int h0 = 4 * bh, w0 = 4 * bw;
            int nh = (bh == 28) ? 2 : 4;
            int nw = (bw == 28) ? 2 : 4;
            float s = 0.0f;
            for (int r2 = 0; r2 < nh; ++r2) {
                const float* p = &Lp[(h0 + r2) * 114 + w0];
                for (int j = 0; j < nw; ++j) s += p[j];
            }
            Lm[b] = (s > -1.0f) ? 1.0f : 0.0f;
        }
    }
    __syncthreads();

    // ---- phase 3: masked writeout (contiguous nontemporal float4 stream) ----
    if (c < 80) {
        for (int i = tid; i < 3249; i += 256) {
            v4 v = *(const v4*)&Lp[4 * i];
            int q = 4 * i;
            int h = q / 114;
            int w = q - h * 114;
            v4 o;
#pragma unroll
            for (int e = 0; e < 4; ++e) {
                o[e] = v[e] * Lm[(h >> 1) * 57 + (w >> 1)];
                ++w;
                if (w == 114) { w = 0; ++h; }   // row carry (float4 may straddle rows)
            }
            __builtin_nontemporal_store(o, &op[i]);
        }
    } else {
        for (int i = tid; i < 3249; i += 256) {
            v4 v = *(const v4*)&Lp[4 * i];
            int q = 4 * i;
            int h = q / 114;
            int w = q - h * 114;
            v4 o;
#pragma unroll
            for (int e = 0; e < 4; ++e) {
                o[e] = v[e] * Lm[(h >> 2) * 29 + (w >> 2)];
                ++w;
                if (w == 114) { w = 0; ++h; }
            }
            __builtin_nontemporal_store(o, &op[i]);
        }
    }
}

extern "C" void kernel_launch(void* const* d_in, const int* in_sizes, int n_in,
                              void* d_out, int out_size, void* d_ws, size_t ws_size,
                              hipStream_t stream) {
    const float* in = (const float*)d_in[0];
    float* out = (float*)d_out;
    sbrelu_plane_kernel<<<2048, 256, 0, stream>>>(in, out);  // 16 n * 128 c planes
}